// Round 1
// baseline (140.641 us; speedup 1.0000x reference)
//
#include <hip/hip_runtime.h>
#include <math.h>

// AutoAttention_Layer: B=1024, MAXLEN=200, F=64, D=64, fp32.
// Algebraic collapse (see theory): v unused; all DxD projections folded to
// per-batch GEMVs; single-pass online softmax (no max-shift needed since
// unmasked logits in (0,0.125) and masked exp underflows to exactly 0).

namespace {
constexpr int MAXLEN = 200;
constexpr int FF     = 64;
constexpr int DD     = 64;
constexpr int TILE   = 64;
constexpr int ROWP   = 65;   // padded LDS row stride (floats): bank stride 1/row -> 2-way max

__global__ __launch_bounds__(256, 8)
void auto_attn_kernel(const float* __restrict__ q,
                      const float* __restrict__ k,
                      const int*   __restrict__ kes_length,
                      const float* __restrict__ fs,
                      const float* __restrict__ bias,
                      const float* __restrict__ Wq,
                      const float* __restrict__ Wk,
                      const float* __restrict__ Wv,
                      float*       __restrict__ out)
{
    __shared__ float kt[TILE * ROWP];   // 16.6 KB: k tile (also reused to stage Wk)
    __shared__ float red[256];
    __shared__ float qbar[DD];
    __shared__ float qw[DD];
    __shared__ float qk[DD];
    __shared__ float kbar[DD];
    __shared__ float sw[TILE];
    __shared__ float sS[4];

    const int tid = threadIdx.x;
    const int b   = blockIdx.x;
    const int d   = tid & 63;
    const int grp = tid >> 6;           // 0..3

    const float* qb = q + (size_t)b * FF * DD;
    const float* kb = k + (size_t)b * MAXLEN * DD;
    const int len   = kes_length[b];

    // ---- qbar[d] = sum_f fs[f] * q[b,f,d]  (coalesced: lanes -> consecutive d)
    float acc = 0.f;
    for (int i = 0; i < 16; ++i) {
        const int f = grp * 16 + i;
        acc += fs[f] * qb[f * 64 + d];
    }
    red[tid] = acc;
    __syncthreads();
    if (tid < 64) qbar[tid] = red[tid] + red[tid + 64] + red[tid + 128] + red[tid + 192];
    __syncthreads();

    // ---- qw[e] = sum_d qbar[d] * Wq[d,e]   (thread's d plays role of e)
    acc = 0.f;
    for (int i = 0; i < 16; ++i) {
        const int dd = grp * 16 + i;
        acc += qbar[dd] * Wq[dd * 64 + d];
    }
    red[tid] = acc;
    __syncthreads();
    if (tid < 64) qw[tid] = red[tid] + red[tid + 64] + red[tid + 128] + red[tid + 192];
    __syncthreads();

    // ---- stage Wk into padded LDS (coalesced float4), then qk[d] = sum_e Wk[d,e]*qw[e]
    for (int j = 0; j < 4; ++j) {
        const int base = (tid + 256 * j) * 4;
        const float4 w4 = *(const float4*)(Wk + base);
        const int row = base >> 6, col = base & 63;
        float* p = &kt[row * ROWP + col];
        p[0] = w4.x; p[1] = w4.y; p[2] = w4.z; p[3] = w4.w;
    }
    __syncthreads();
    acc = 0.f;
    for (int i = 0; i < 16; ++i) {
        const int e = grp * 16 + i;
        acc += kt[d * ROWP + e] * qw[e];   // banks (d+e)%32 -> 2-way, free
    }
    red[tid] = acc;
    __syncthreads();
    if (tid < 64) qk[tid] = red[tid] + red[tid + 64] + red[tid + 128] + red[tid + 192];
    __syncthreads();

    const float bscale = bias[0] * 64.0f;

    // ---- single pass over k: accumulate S = sum_t w[t], kacc[d] = sum_t w[t]*k[t,d]
    float kaccr = 0.f;   // this thread's (d, token-group grp) partial
    float Sr    = 0.f;   // per-grp weight sum (redundant across the 64 d-lanes)
    const int tok = tid >> 2;          // 0..63 : one token per 4 threads
    const int dq  = (tid & 3) << 4;    // 16-elem slice of the dot product

    for (int tile = 0; tile < 4; ++tile) {
        const int t0   = tile * TILE;
        const int tlen = min(TILE, MAXLEN - t0);     // 64,64,64,8
        // stage tile (float4 global -> padded LDS)
        for (int j = tid; j < tlen * 16; j += 256) {
            const int base = j * 4;
            const float4 kv = *(const float4*)(kb + t0 * 64 + base);
            const int row = base >> 6, col = base & 63;
            float* p = &kt[row * ROWP + col];
            p[0] = kv.x; p[1] = kv.y; p[2] = kv.z; p[3] = kv.w;
        }
        __syncthreads();
        // scores: 4-lane split dot + butterfly, then weight
        if (tok < tlen) {
            float s = 0.f;
            const float* rowp = &kt[tok * ROWP + dq];
            for (int i = 0; i < 16; ++i) s += rowp[i] * qk[dq + i];
            s += __shfl_xor(s, 1);
            s += __shfl_xor(s, 2);
            s += bscale;
            const int t = t0 + tok;
            float w;
            if (len == 0)      w = 1.0f;                       // uniform softmax case
            else if (t < len) { const float sig = 1.0f / (1.0f + expf(-s));
                                w = expf(sig * 0.125f); }      // exp needs no max-shift
            else               w = 0.0f;                       // masked -> exactly 0
            if ((tid & 3) == 0) sw[tok] = w;
        }
        __syncthreads();
        // accumulate kacc and S
        const int nt = min(16, tlen - grp * 16);
        for (int i = 0; i < nt; ++i) {
            const int tl = grp * 16 + i;
            const float w = sw[tl];        // broadcast
            kaccr += w * kt[tl * ROWP + d];
            Sr    += w;
        }
        __syncthreads();   // before next tile overwrites kt/sw
    }

    // ---- reduce kacc over token-groups, normalize, project through Wv
    red[tid] = kaccr;
    if (d == 0) sS[grp] = Sr;
    __syncthreads();
    if (tid < 64) {
        const float kv = red[tid] + red[tid + 64] + red[tid + 128] + red[tid + 192];
        const float S  = sS[0] + sS[1] + sS[2] + sS[3];   // >= 1 always (len==0 -> 200)
        kbar[tid] = kv / S;
    }
    __syncthreads();
    acc = 0.f;
    for (int i = 0; i < 16; ++i) {
        const int dd = grp * 16 + i;
        acc += kbar[dd] * Wv[dd * 64 + d];
    }
    red[tid] = acc;
    __syncthreads();
    if (tid < 64) out[(size_t)b * 64 + tid] = red[tid] + red[tid + 64] + red[tid + 128] + red[tid + 192];
}
} // namespace

extern "C" void kernel_launch(void* const* d_in, const int* in_sizes, int n_in,
                              void* d_out, int out_size, void* d_ws, size_t ws_size,
                              hipStream_t stream) {
    const float* q    = (const float*)d_in[0];
    const float* k    = (const float*)d_in[1];
    // d_in[2] = v : provably unused by the reference (vp is computed from k)
    const int*   kes  = (const int*)  d_in[3];
    const float* fs   = (const float*)d_in[4];
    const float* bias = (const float*)d_in[5];
    const float* Wq   = (const float*)d_in[6];
    const float* Wk   = (const float*)d_in[7];
    const float* Wv   = (const float*)d_in[8];
    float* out = (float*)d_out;

    auto_attn_kernel<<<dim3(1024), dim3(256), 0, stream>>>(q, k, kes, fs, bias, Wq, Wk, Wv, out);
}